// Round 7
// baseline (139.004 us; speedup 1.0000x reference)
//
#include <hip/hip_runtime.h>

typedef unsigned short u16;
typedef unsigned int u32;
typedef __attribute__((ext_vector_type(8))) short bf16x8;
typedef __attribute__((ext_vector_type(4))) short bf16x4;
typedef __attribute__((ext_vector_type(4))) float f32x4;

#define MFMA(a, b, c) __builtin_amdgcn_mfma_f32_16x16x32_bf16((a), (b), (c), 0, 0, 0)
#define MFMA16(a, b, c) __builtin_amdgcn_mfma_f32_16x16x16bf16_1k((a), (b), (c), 0, 0, 0)

// round-to-nearest-even f32 -> bf16
static __device__ __forceinline__ u16 f2bf(float x) {
  u32 u = __float_as_uint(x);
  u += 0x7FFFu + ((u >> 16) & 1u);
  return (u16)(u >> 16);
}
// pack two f32 -> (bf16(hi)<<16)|bf16(lo), truncating (hot paths)
static __device__ __forceinline__ u32 packbf_t(float hi, float lo) {
  return __builtin_amdgcn_perm(__float_as_uint(hi), __float_as_uint(lo), 0x07060302u);
}
// rounded pack: lo | hi<<16
static __device__ __forceinline__ u32 packbf(float lo, float hi) {
  return (u32)f2bf(lo) | ((u32)f2bf(hi) << 16);
}

// ---------------------------------------------------------------------------
// Kernel 0: weight prep (bf16 conversion + gate-major permute of Wm).
// ---------------------------------------------------------------------------
__global__ void prep_kernel(const float* __restrict__ Wq, const float* __restrict__ Wk,
                            const float* __restrict__ Wk2, const float* __restrict__ Wv,
                            const float* __restrict__ Wv2, const float* __restrict__ Wz,
                            const float* __restrict__ Wm, const float* __restrict__ bm,
                            u16* __restrict__ W5, u16* __restrict__ Wzb,
                            u16* __restrict__ Wmb, float* __restrict__ bmp) {
  const int id = blockIdx.x * 256 + threadIdx.x;
  if (id < 20480) {
    const int wi = id >> 12, e = id & 4095;
    const float* src = wi == 0 ? Wq : wi == 1 ? Wk : wi == 2 ? Wk2 : wi == 3 ? Wv : Wv2;
    W5[id] = f2bf(src[e]);
  } else if (id < 36864) {
    const int e = id - 20480;
    Wzb[e] = f2bf(Wz[e]);
  } else if (id < 73728) {
    const int e = id - 36864;
    const int p = e / 192, k = e % 192;
    const int hb2 = p / 96, r1 = p % 96, ctl = r1 / 48, r2 = r1 % 48;
    const int g = r2 >> 4, mm = r2 & 15;
    const int o = g * 64 + (hb2 * 2 + ctl) * 16 + mm;
    Wmb[p * 192 + k] = f2bf(Wm[o * 192 + k]);
  } else if (id < 73920) {
    const int p = id - 73728;
    const int hb2 = p / 96, r1 = p % 96, ctl = r1 / 48, r2 = r1 % 48;
    const int g = r2 >> 4, mm = r2 & 15;
    const int o = g * 64 + (hb2 * 2 + ctl) * 16 + mm;
    bmp[p] = bm[o];
  }
}

// ---------------------------------------------------------------------------
// Kernel 1: 1x1-conv projections via bf16 MFMA, packed uint2 stores.
// Q/K: (B,N,64). V: BLOCKED (b, kc=n/64, c, 64keys).
// grid (16 b, 16 nt, 2): blockIdx.x = b so linear%8 == b%8 -> the XCD that
// writes Q/K/V for batch b is the XCD attn reads them on (L2 locality).
// ---------------------------------------------------------------------------
__global__ __launch_bounds__(256) void proj_kernel(
    const float* __restrict__ h, const float* __restrict__ m_,
    const float* __restrict__ bq, const float* __restrict__ bk,
    const float* __restrict__ bk2, const float* __restrict__ bv,
    const float* __restrict__ bv2, const u16* __restrict__ W5,
    u16* __restrict__ Qb, u16* __restrict__ Khb, u16* __restrict__ Kmb,
    u16* __restrict__ Vhb, u16* __restrict__ Vmb, u16* __restrict__ hbuf)
{
  const int b = blockIdx.x, nt = blockIdx.y, n0 = nt * 64, z = blockIdx.z;
  __shared__ __align__(16) u16 xt[64][72];  // [px][c] bf16
  const int tid = threadIdx.x;
  const float* __restrict__ X = z ? m_ : h;

  {
    const int px = tid & 63, c0 = (tid >> 6) * 16;
#pragma unroll
    for (int i = 0; i < 8; ++i) {
      const int c = c0 + 2 * i;
      const float f0 = X[(b * 64 + c) * 1024 + n0 + px];
      const float f1 = X[(b * 64 + c + 1) * 1024 + n0 + px];
      *(u32*)&xt[px][c] = packbf(f0, f1);
    }
  }
  __syncthreads();

  const int lane = tid & 63, w = tid >> 6;  // w = 16-px tile
  const int mm = lane & 15, q = lane >> 4;

  const bf16x8 xa0 = *(const bf16x8*)&xt[w * 16 + mm][q * 8];
  const bf16x8 xa1 = *(const bf16x8*)&xt[w * 16 + mm][32 + q * 8];

  auto qk_store = [&](u16* dst, const u16* Wb, const float* bias) {
#pragma unroll
    for (int ot = 0; ot < 4; ++ot) {
      const bf16x8 wb0 = *(const bf16x8*)(Wb + (ot * 16 + mm) * 64 + q * 8);
      const bf16x8 wb1 = *(const bf16x8*)(Wb + (ot * 16 + mm) * 64 + 32 + q * 8);
      const float4 b4 = *(const float4*)(bias + ot * 16 + q * 4);
      f32x4 d = {b4.x, b4.y, b4.z, b4.w};
      d = MFMA(wb0, xa0, d);
      d = MFMA(wb1, xa1, d);
      uint2 val;
      val.x = packbf(d[0], d[1]);
      val.y = packbf(d[2], d[3]);
      *(uint2*)(dst + (b * 1024 + n0 + w * 16 + mm) * 64 + ot * 16 + q * 4) = val;
    }
  };
  auto v_store = [&](u16* dst, const u16* Wb, const float* bias) {
#pragma unroll
    for (int ot = 0; ot < 4; ++ot) {
      const bf16x8 wb0 = *(const bf16x8*)(Wb + (ot * 16 + mm) * 64 + q * 8);
      const bf16x8 wb1 = *(const bf16x8*)(Wb + (ot * 16 + mm) * 64 + 32 + q * 8);
      const float bb = bias[ot * 16 + mm];
      f32x4 d = {bb, bb, bb, bb};
      d = MFMA(xa0, wb0, d);
      d = MFMA(xa1, wb1, d);
      uint2 val;
      val.x = packbf(d[0], d[1]);
      val.y = packbf(d[2], d[3]);
      *(uint2*)(dst + b * 65536 + nt * 4096 + (ot * 16 + mm) * 64 +
                w * 16 + q * 4) = val;
    }
  };

  if (z == 0) {
    qk_store(Qb, W5, bq);
    qk_store(Khb, W5 + 4096, bk);
    v_store(Vhb, W5 + 3 * 4096, bv);
    const int px = tid >> 2, sg = tid & 3;
    u32* dst = (u32*)(hbuf + (b * 1024 + n0 + px) * 64 + sg * 16);
    const u16* srcr = &xt[px][sg * 16];
#pragma unroll
    for (int j = 0; j < 8; ++j) dst[j] = *(const u32*)(srcr + 2 * j);
  } else {
    qk_store(Kmb, W5 + 2 * 4096, bk2);
    v_store(Vmb, W5 + 4 * 4096, bv2);
  }
}

// ---------------------------------------------------------------------------
// Kernel 2: fused attention, key-split flash, zero-transpose PV.
// Block = 32 queries x 4 waves (wave w owns a 16-key slice of each 64-key
// chunk, 2 query tiles). LDS 37.4 KB -> 4 blocks/CU (4 waves/SIMD, 2x r6's
// occupancy) for latency hiding across the per-chunk barrier.
// grid 1024 = 16 b (XCD-affine, matches proj's writers) x 2 br x 32 qh.
// ---------------------------------------------------------------------------
__global__ __launch_bounds__(256) void attn_kernel(
    const u16* __restrict__ Qb, const u16* __restrict__ Khb,
    const u16* __restrict__ Kmb, const u16* __restrict__ Vhb,
    const u16* __restrict__ Vmb, u16* __restrict__ Ztb)
{
  const int id = blockIdx.x;
  const int b = id & 15;            // batch -> fixed XCD (id%8 == b%8)
  const int br = (id >> 4) & 1;
  const int qh = id >> 5;           // 0..31
  const u16* __restrict__ K = (br ? Kmb : Khb) + b * 65536;  // (N,64)
  const u16* __restrict__ V = (br ? Vmb : Vhb) + b * 65536;  // blocked (kc,c,64)

  __shared__ __align__(16) u16 pool[18432];  // Kl[2][64][72] + Vl[2][64][72] / zcb
  __shared__ float rsw[4][32];
  u16* const Kl = pool;            // 2 * 4608 u16
  u16* const Vl = pool + 9216;     // 2 * 4608 u16

  const int tid = threadIdx.x, w = tid >> 6, lane = tid & 63;
  const int mm = lane & 15, q = lane >> 4;
  const int q0 = qh * 32;

  // Q B-operand frags for 2 query tiles: B[n=query=mm][k=d=q*8+j]
  bf16x8 qb0[2], qb1[2];
#pragma unroll
  for (int qt = 0; qt < 2; ++qt) {
    const u16* Qp = Qb + (b * 1024 + q0 + qt * 16 + mm) * 64;
    qb0[qt] = *(const bf16x8*)(Qp + q * 8);
    qb1[qt] = *(const bf16x8*)(Qp + 32 + q * 8);
  }

  f32x4 z[2][4];  // [qt][ct] = Z[c=ct*16+q*4+r][query=qt*16+mm] partial
#pragma unroll
  for (int qt = 0; qt < 2; ++qt)
#pragma unroll
    for (int ct = 0; ct < 4; ++ct) z[qt][ct] = (f32x4){0.f, 0.f, 0.f, 0.f};
  float rp[2] = {0.f, 0.f};

  // staging: 512 16B-units K + 512 V; padded rows of 72 (<=2-way banks).
  const int so0 = (tid >> 3) * 72 + (tid & 7) * 8;
  const int so1 = so0 + 32 * 72;
  uint4 sk0, sk1, sv0, sv1;
  auto stage_load = [&](int kc) {
    const u16* Ks = K + kc * 4096;
    const u16* Vs = V + kc * 4096;
    sk0 = *(const uint4*)(Ks + tid * 8);
    sk1 = *(const uint4*)(Ks + tid * 8 + 2048);
    sv0 = *(const uint4*)(Vs + tid * 8);
    sv1 = *(const uint4*)(Vs + tid * 8 + 2048);
  };
  auto stage_store = [&](int buf) {
    u16* Kd = Kl + buf * 4608;
    u16* Vd = Vl + buf * 4608;
    *(uint4*)(Kd + so0) = sk0;
    *(uint4*)(Kd + so1) = sk1;
    *(uint4*)(Vd + so0) = sv0;
    *(uint4*)(Vd + so1) = sv1;
  };

  stage_load(0);
  stage_store(0);
  __syncthreads();

  int cur = 0;
#pragma unroll 1
  for (int kc = 0; kc < 16; ++kc) {
    if (kc < 15) stage_load(kc + 1);

    const u16* Kc = Kl + cur * 4608;
    const u16* Vc = Vl + cur * 4608;
    // A-operand K frags for this wave's 16-key slice: A[m=key=mm][k=d]
    const bf16x8 kf0 = *(const bf16x8*)(Kc + (w * 16 + mm) * 72 + q * 8);
    const bf16x8 kf1 = *(const bf16x8*)(Kc + (w * 16 + mm) * 72 + 32 + q * 8);
    // A-operand V frags: A[m=c=mm][k=key=q*4+i] for this wave's slice
    bf16x4 vf[4];
#pragma unroll
    for (int ct = 0; ct < 4; ++ct)
      vf[ct] = *(const bf16x4*)(Vc + (ct * 16 + mm) * 72 + w * 16 + q * 4);

#pragma unroll
    for (int qt = 0; qt < 2; ++qt) {
      f32x4 s = {0.f, 0.f, 0.f, 0.f};
      s = MFMA(kf0, qb0[qt], s);
      s = MFMA(kf1, qb1[qt], s);
      const float e0 = __expf(s[0]), e1 = __expf(s[1]);
      const float e2 = __expf(s[2]), e3 = __expf(s[3]);
      rp[qt] += (e0 + e1) + (e2 + e3);
      union { u32 u[2]; bf16x4 v; } pb;
      pb.u[0] = packbf_t(e1, e0);   // B[k=q*4+{0,1}][n=mm]
      pb.u[1] = packbf_t(e3, e2);   // B[k=q*4+{2,3}][n=mm]
#pragma unroll
      for (int ct = 0; ct < 4; ++ct) z[qt][ct] = MFMA16(vf[ct], pb.v, z[qt][ct]);
    }

    if (kc < 15) stage_store(cur ^ 1);
    __syncthreads();
    cur ^= 1;
  }

  // publish: zcb overlays the (dead) stage buffers. [w][query(32)][c], rows 68.
  u16* const zcb = pool;
#pragma unroll
  for (int qt = 0; qt < 2; ++qt) {
    float v = rp[qt];
    v += __shfl_xor(v, 16);
    v += __shfl_xor(v, 32);
    if (q == 0) rsw[w][qt * 16 + mm] = v;
#pragma unroll
    for (int ct = 0; ct < 4; ++ct) {
      uint2 val;
      val.x = packbf_t(z[qt][ct][1], z[qt][ct][0]);
      val.y = packbf_t(z[qt][ct][3], z[qt][ct][2]);
      *(uint2*)(zcb + w * 2176 + (qt * 16 + mm) * 68 + ct * 16 + q * 4) = val;
    }
  }
  __syncthreads();

  // combine 4 key-splits, normalize, store bf16 (B,N,128)
  const int c2 = tid & 31, qr = tid >> 5;
#pragma unroll
  for (int i = 0; i < 4; ++i) {
    const int query = qr + i * 8;
    const float rt = rsw[0][query] + rsw[1][query] + rsw[2][query] + rsw[3][query];
    const float rinv = __builtin_amdgcn_rcpf(rt);
    float vlo = 0.f, vhi = 0.f;
#pragma unroll
    for (int ww = 0; ww < 4; ++ww) {
      const u32 u = *(const u32*)(zcb + ww * 2176 + query * 68 + c2 * 2);
      vlo += __uint_as_float(u << 16);
      vhi += __uint_as_float(u & 0xffff0000u);
    }
    vlo *= rinv;
    vhi *= rinv;
    *(u32*)(Ztb + (b * 1024 + q0 + query) * 128 + br * 64 + c2 * 2) = packbf_t(vhi, vlo);
  }
}

// ---------------------------------------------------------------------------
// Kernel 3: fused zproj (128->128) + final (192->192) + gates, all MFMA.
// grid (16 b, 32 nt): linear%8 == b%8 matches attn's Ztb writers (L2 local).
// ---------------------------------------------------------------------------
__global__ __launch_bounds__(256) void tail_kernel(
    const u16* __restrict__ Ztb, const u16* __restrict__ hbuf,
    const float* __restrict__ m_, const u16* __restrict__ Wzb,
    const float* __restrict__ bz, const u16* __restrict__ Wmb,
    const float* __restrict__ bmp, float* __restrict__ out)
{
  const int b = blockIdx.x, n0 = blockIdx.y * 32;
  __shared__ __align__(16) u16 zp[32][136];  // bf16 Zp tile [px][c]
  const int tid = threadIdx.x, lane = tid & 63, wv = tid >> 6;
  const int mm = lane & 15, q = lane >> 4;
  const int pxt = wv & 1, oh = wv >> 1;

  // ---- Phase A: Zp = Wz @ [Zh;Zm] + bz  (A=W: lane rows = contiguous o-ch)
  {
    bf16x8 za[4];
#pragma unroll
    for (int ks = 0; ks < 4; ++ks)
      za[ks] = *(const bf16x8*)(Ztb + (b * 1024 + n0 + pxt * 16 + mm) * 128 +
                                ks * 32 + q * 8);
#pragma unroll
    for (int ot = 0; ot < 4; ++ot) {
      const int o0 = oh * 64 + ot * 16;
      const float4 b4 = *(const float4*)(bz + o0 + q * 4);
      f32x4 d = {b4.x, b4.y, b4.z, b4.w};
#pragma unroll
      for (int ks = 0; ks < 4; ++ks) {
        const bf16x8 wb = *(const bf16x8*)(Wzb + (o0 + mm) * 128 + ks * 32 + q * 8);
        d = MFMA(wb, za[ks], d);
      }
      uint2 val;
      val.x = packbf(d[0], d[1]);
      val.y = packbf(d[2], d[3]);
      *(uint2*)&zp[pxt * 16 + mm][o0 + q * 4] = val;
    }
  }
  __syncthreads();

  // ---- Phase B: combined = Wm @ [Zp; h] + bm (rows gate-major-permuted)
  {
    const int hb2 = oh;
    bf16x8 fa[6];
#pragma unroll
    for (int ks = 0; ks < 4; ++ks)
      fa[ks] = *(const bf16x8*)&zp[pxt * 16 + mm][ks * 32 + q * 8];
    {
      const u16* hp = hbuf + (b * 1024 + n0 + pxt * 16 + mm) * 64;
      fa[4] = *(const bf16x8*)(hp + q * 8);
      fa[5] = *(const bf16x8*)(hp + 32 + q * 8);
    }
    f32x4 dd[6];
#pragma unroll
    for (int j = 0; j < 6; ++j) {
      const int p = hb2 * 96 + j * 16 + mm;
      const float bb = bmp[p];
      f32x4 d = {bb, bb, bb, bb};
#pragma unroll
      for (int ks = 0; ks < 6; ++ks) {
        const bf16x8 wb = *(const bf16x8*)(Wmb + p * 192 + ks * 32 + q * 8);
        d = MFMA(fa[ks], wb, d);
      }
      dd[j] = d;
    }
#pragma unroll
    for (int ctl = 0; ctl < 2; ++ctl) {
      const int c = (hb2 * 2 + ctl) * 16 + mm;
      const int px = n0 + pxt * 16 + q * 4;
      const float4 mold = *(const float4*)(m_ + (b * 64 + c) * 1024 + px);
      float4 nh, nm;
#pragma unroll
      for (int r = 0; r < 4; ++r) {
        const float xo = dd[ctl * 3 + 0][r];
        const float xg = dd[ctl * 3 + 1][r];
        const float xi = dd[ctl * 3 + 2][r];
        const float si = __builtin_amdgcn_rcpf(1.f + __expf(-xi));
        const float th = 1.f - 2.f * __builtin_amdgcn_rcpf(__expf(2.f * xg) + 1.f);
        const float so = __builtin_amdgcn_rcpf(1.f + __expf(-xo));
        const float mo = ((const float*)&mold)[r];
        const float nmv = (1.f - si) * mo + si * th;
        ((float*)&nm)[r] = nmv;
        ((float*)&nh)[r] = so * nmv;
      }
      *(float4*)(out + (b * 64 + c) * 1024 + px) = nh;
      *(float4*)(out + 1048576 + (b * 64 + c) * 1024 + px) = nm;
    }
  }
}

// ---------------------------------------------------------------------------
extern "C" void kernel_launch(void* const* d_in, const int* in_sizes, int n_in,
                              void* d_out, int out_size, void* d_ws, size_t ws_size,
                              hipStream_t stream) {
  const float* h   = (const float*)d_in[0];
  const float* m   = (const float*)d_in[1];
  const float* Wq  = (const float*)d_in[2];
  const float* bq  = (const float*)d_in[3];
  const float* Wk  = (const float*)d_in[4];
  const float* bk  = (const float*)d_in[5];
  const float* Wk2 = (const float*)d_in[6];
  const float* bk2 = (const float*)d_in[7];
  const float* Wv  = (const float*)d_in[8];
  const float* bv  = (const float*)d_in[9];
  const float* Wv2 = (const float*)d_in[10];
  const float* bv2 = (const float*)d_in[11];
  const float* Wz  = (const float*)d_in[12];
  const float* bz  = (const float*)d_in[13];
  const float* Wm  = (const float*)d_in[14];
  const float* bm  = (const float*)d_in[15];
  float* out = (float*)d_out;

  char* ws = (char*)d_ws;
  const size_t MB = 1024 * 1024;
  u16* Qb   = (u16*)(ws + 0 * MB);       // (B,N,64)
  u16* Khb  = (u16*)(ws + 2 * MB);
  u16* Kmb  = (u16*)(ws + 4 * MB);
  u16* Vhb  = (u16*)(ws + 6 * MB);       // blocked (b,kc,c,64)
  u16* Vmb  = (u16*)(ws + 8 * MB);
  u16* hbuf = (u16*)(ws + 10 * MB);      // (B,N,64)
  u16* Ztb  = (u16*)(ws + 12 * MB);      // (B,N,128)
  u16* W5   = (u16*)(ws + 16 * MB);               // 5x 64x64 bf16
  u16* Wzb  = (u16*)(ws + 16 * MB + 40960);       // 128x128
  u16* Wmb  = (u16*)(ws + 16 * MB + 73728);       // 192x192 permuted
  float* bmp = (float*)(ws + 16 * MB + 147456);   // 192 permuted

  prep_kernel<<<289, 256, 0, stream>>>(Wq, Wk, Wk2, Wv, Wv2, Wz, Wm, bm,
                                       W5, Wzb, Wmb, bmp);
  proj_kernel<<<dim3(16, 16, 2), 256, 0, stream>>>(h, m, bq, bk, bk2, bv, bv2, W5,
                                                   Qb, Khb, Kmb, Vhb, Vmb, hbuf);
  attn_kernel<<<1024, 256, 0, stream>>>(Qb, Khb, Kmb, Vhb, Vmb, Ztb);
  tail_kernel<<<dim3(16, 32), 256, 0, stream>>>(Ztb, hbuf, m, Wzb, bz, Wmb, bmp, out);
}